// Round 13
// baseline (1900.380 us; speedup 1.0000x reference)
//
#include <hip/hip_runtime.h>
#include <stdint.h>

#define NE 195480
#define NM 10242
#define NG 65160
#define DD 512
#define NOUT 471

typedef __attribute__((ext_vector_type(8))) short bf16x8;
typedef __attribute__((ext_vector_type(4))) float f32x4;
typedef __attribute__((ext_vector_type(8))) unsigned short ushort8;

__device__ __forceinline__ float bf2f(unsigned short u) {
    union { unsigned int i; float f; } v; v.i = ((unsigned int)u) << 16; return v.f;
}
__device__ __forceinline__ unsigned short f2bf(float f) {
    union { float f; unsigned int u; } v; v.f = f;
    unsigned int x = v.u;
    return (unsigned short)((x + 0x7fffu + ((x >> 16) & 1u)) >> 16);
}
__device__ __forceinline__ float silu_f(float x) { return x / (1.f + __expf(-x)); }

__device__ __forceinline__ ushort8 cvt8(const float* __restrict__ p) {
    const f32x4 lo = *(const f32x4*)p;
    const f32x4 hi = *(const f32x4*)(p + 4);
    ushort8 r;
    #pragma unroll
    for (int j = 0; j < 4; ++j) { r[j] = f2bf(lo[j]); r[j + 4] = f2bf(hi[j]); }
    return r;
}

// async global->LDS, 16B per lane. LDS dest lane-linear; global src per-lane.
__device__ __forceinline__ void gl_lds16(const unsigned short* g, unsigned short* l) {
    __builtin_amdgcn_global_load_lds(
        (const __attribute__((address_space(1))) unsigned int*)g,
        (__attribute__((address_space(3))) unsigned int*)l, 16, 0, 0);
}

enum { A_PLAIN = 0, A_NODE = 1 };
enum { E_BIAS_BF16 = 0, E_SILU_BF16 = 1, E_AGG_BF16 = 2, E_RESID_BF16 = 3,
       E_OUT_F32 = 4, E_EDGE_SILU = 5 };

// C = epilogue(A @ B + bias), 128x128 tile, BK=64, 4 waves (2x2).
// 1D grid + bijective chunked XCD swizzle (R11: FETCH 3.2x cut, verified).
// m97-style global_load_lds staging, source-chunk swizzle, 0 bank conflicts.
// E_EDGE_SILU (R13): out = silu(acc + meshP[esrc[row]] + gridP[edst[row]]).
//   Row index is quadrant-uniform (no per-lane divergence); 16-lane col reads
//   are 32B contiguous; meshP/gridP are mostly L3-resident. This moves the
//   src/dst projections out of the per-edge GEMM (K 1536 -> 512).
// E_AGG_BF16: v = acc + deg[row]*bias[col].
template<int AMODE, int EPI>
__global__ __launch_bounds__(256)
void gemm128(const unsigned short* __restrict__ Asrc,   // PLAIN: A | NODE: src0
             const unsigned short* __restrict__ Asrc2,  // NODE: src1
             const unsigned short* __restrict__ Bw,     // bf16 [512][K]
             const float* __restrict__ bias,
             int M, int N, int K, int ldOut,
             const float* __restrict__ gridres,         // E_RESID residual (f32)
             const int* __restrict__ esrc,
             const int* __restrict__ edst,
             const unsigned* __restrict__ degA,         // E_AGG per-row count
             const unsigned short* __restrict__ mP,     // E_EDGE_SILU gather (bf16)
             const unsigned short* __restrict__ gP,     // E_EDGE_SILU gather (bf16)
             unsigned short* __restrict__ outB,
             float* __restrict__ outF)
{
    __shared__ unsigned short As[128 * 64];
    __shared__ unsigned short Bs[128 * 64];

    const int tid  = threadIdx.x;
    const int nwg  = gridDim.x;
    int orig = blockIdx.x;
    if ((nwg & 7) == 0) {                       // bijective chunked XCD swizzle
        const int q = nwg >> 3;
        orig = (blockIdx.x & 7) * q + (blockIdx.x >> 3);
    }
    const int bn = orig & 3;
    const int bm = orig >> 2;

    const int w    = tid >> 6;
    const int lane = tid & 63;
    const int quad = lane >> 4;
    const int ln   = lane & 15;
    const int wr   = w >> 1;
    const int wc   = w & 1;

    const int srow = tid >> 3;    // 0..31
    const int sc   = tid & 7;     // 0..7
    const int ck   = (sc ^ (srow & 7)) * 8;   // swizzled source chunk (elems)

    int arowc[4];
    #pragma unroll
    for (int i = 0; i < 4; ++i) {
        int r = bm * 128 + i * 32 + srow;
        arowc[i] = (r < M) ? r : (M - 1);
    }

    f32x4 acc[4][4] = {};

    for (int k0 = 0; k0 < K; k0 += 64) {
        __syncthreads();   // previous compute done reading LDS
        #pragma unroll
        for (int i = 0; i < 4; ++i) {
            const int row = i * 32 + srow;
            const unsigned short* ga;
            if (AMODE == A_PLAIN) {
                ga = Asrc + (size_t)arowc[i] * K + k0 + ck;
            } else { // A_NODE: [src0 | src1] both bf16, stride 512
                if (k0 < 512)       ga = Asrc  + (size_t)arowc[i] * 512 + k0 + ck;
                else                ga = Asrc2 + (size_t)arowc[i] * 512 + (k0 - 512) + ck;
            }
            gl_lds16(ga, As + i * 2048 + tid * 8);
            gl_lds16(Bw + (size_t)(bn * 128 + row) * K + k0 + ck, Bs + i * 2048 + tid * 8);
        }
        __syncthreads();   // vmcnt(0) drained before barrier -> staged

        #pragma unroll
        for (int kt = 0; kt < 2; ++kt) {
            bf16x8 af[4], bfv[4];
            #pragma unroll
            for (int m = 0; m < 4; ++m) {
                const int r = wr * 64 + m * 16 + ln;
                af[m] = *(const bf16x8*)(As + r * 64 + (((kt * 4 + quad) ^ (r & 7)) * 8));
            }
            #pragma unroll
            for (int n = 0; n < 4; ++n) {
                const int r = wc * 64 + n * 16 + ln;
                bfv[n] = *(const bf16x8*)(Bs + r * 64 + (((kt * 4 + quad) ^ (r & 7)) * 8));
            }
            #pragma unroll
            for (int m = 0; m < 4; ++m)
                #pragma unroll
                for (int n = 0; n < 4; ++n)
                    acc[m][n] = __builtin_amdgcn_mfma_f32_16x16x32_bf16(af[m], bfv[n], acc[m][n], 0, 0, 0);
        }
    }

    // ---- epilogue ----
    int colg[4]; float bcol[4]; bool cok[4];
    #pragma unroll
    for (int n = 0; n < 4; ++n) {
        colg[n] = bn * 128 + wc * 64 + n * 16 + ln;
        cok[n]  = (colg[n] < N);
        bcol[n] = cok[n] ? bias[colg[n]] : 0.f;
    }
    #pragma unroll
    for (int m = 0; m < 4; ++m) {
        #pragma unroll
        for (int r = 0; r < 4; ++r) {
            const int row_g = bm * 128 + wr * 64 + m * 16 + quad * 4 + r;
            if (row_g >= M) continue;
            int se = 0, de = 0;
            if (EPI == E_EDGE_SILU) { se = esrc[row_g]; de = edst[row_g]; }
            const float degb = (EPI == E_AGG_BF16) ? (float)degA[row_g] : 1.f;
            #pragma unroll
            for (int n = 0; n < 4; ++n) {
                if (!cok[n]) continue;
                float v = acc[m][n][r] + degb * bcol[n];
                if (EPI == E_BIAS_BF16 || EPI == E_AGG_BF16) {
                    outB[(size_t)row_g * ldOut + colg[n]] = f2bf(v);
                } else if (EPI == E_SILU_BF16) {
                    outB[(size_t)row_g * ldOut + colg[n]] = f2bf(silu_f(v));
                } else if (EPI == E_EDGE_SILU) {
                    v += bf2f(mP[(size_t)se * 512 + colg[n]])
                       + bf2f(gP[(size_t)de * 512 + colg[n]]);
                    outB[(size_t)row_g * ldOut + colg[n]] = f2bf(silu_f(v));
                } else if (EPI == E_RESID_BF16) {
                    v += gridres[(size_t)row_g * 512 + colg[n]];
                    outB[(size_t)row_g * ldOut + colg[n]] = f2bf(v);
                } else { // E_OUT_F32
                    outF[(size_t)row_g * N + colg[n]] = v;
                }
            }
        }
    }
}

// Transpose-convert: w f32 [K][N] -> wT bf16 [Npad][K-slice], row stride ldT.
__global__ __launch_bounds__(256)
void wconv(const float* __restrict__ w, unsigned short* __restrict__ wT,
           int K, int N, int Npad, int ldT)
{
    __shared__ float t[64][65];
    const int tid = threadIdx.x;
    const int bk = blockIdx.x * 64, bn = blockIdx.y * 64;
    const int cc = tid & 63, rr = tid >> 6;
    #pragma unroll
    for (int i = 0; i < 16; ++i) {
        const int k = rr + i * 4;
        float v = 0.f;
        if (bk + k < K && bn + cc < N) v = w[(size_t)(bk + k) * N + bn + cc];
        t[k][cc] = v;
    }
    __syncthreads();
    #pragma unroll
    for (int i = 0; i < 16; ++i) {
        const int n = rr + i * 4;
        if (bn + n < Npad && bk + cc < K)
            wT[(size_t)(bn + n) * ldT + bk + cc] = f2bf(t[cc][n]);
    }
}

// flat f32 -> bf16 convert, 8 elems/thread
__global__ __launch_bounds__(256)
void cvtb(const float* __restrict__ in, unsigned short* __restrict__ out, long long n8)
{
    const long long i = (long long)blockIdx.x * 256 + threadIdx.x;
    if (i >= n8) return;
    *(ushort8*)(out + i * 8) = cvt8(in + i * 8);
}

// h1 = silu(attrs @ emb_w0 + emb_b0), K=4
__global__ __launch_bounds__(256)
void embed_l1(const float* __restrict__ attrs,
              const float* __restrict__ w0,
              const float* __restrict__ b0,
              unsigned short* __restrict__ h)
{
    const long long idx = (long long)blockIdx.x * 256 + threadIdx.x;
    if (idx >= (long long)NE * 512) return;
    const int row = (int)(idx >> 9);
    const int c = (int)(idx & 511);
    float acc = b0[c];
    #pragma unroll
    for (int k = 0; k < 4; ++k)
        acc += attrs[row * 4 + k] * w0[k * 512 + c];
    h[idx] = f2bf(silu_f(acc));
}

// Per-dst-node slot lists: fill[d] counter + slots[d][0..63] edge ids.
__global__ __launch_bounds__(256)
void fillslots(const int* __restrict__ edst, unsigned* __restrict__ fill,
               unsigned* __restrict__ slots)
{
    const int i = blockIdx.x * 256 + threadIdx.x;
    if (i >= NE) return;
    const int d = edst[i];
    const unsigned p = atomicAdd(&fill[d], 1u);
    if (p < 64u) slots[(size_t)d * 64 + p] = (unsigned)i;
}

// Fused segment-sums of BOTH h1 and hb3 (bf16 rows, f32 accum).
__global__ __launch_bounds__(256)
void segsum2(const unsigned short* __restrict__ h1,
             const unsigned short* __restrict__ h3,
             const unsigned* __restrict__ fill,
             const unsigned* __restrict__ slots,
             unsigned short* __restrict__ s1,
             unsigned short* __restrict__ s3)
{
    const int g = blockIdx.x;
    const int c = threadIdx.x;
    unsigned deg = fill[g]; if (deg > 64u) deg = 64u;
    float a0 = 0.f, a1 = 0.f, b0 = 0.f, b1 = 0.f;
    for (unsigned j = 0; j < deg; ++j) {
        const size_t row = (size_t)slots[(size_t)g * 64 + j] * 512;
        a0 += bf2f(h1[row + c]);
        a1 += bf2f(h1[row + c + 256]);
        b0 += bf2f(h3[row + c]);
        b1 += bf2f(h3[row + c + 256]);
    }
    s1[(size_t)g * 512 + c]       = f2bf(a0);
    s1[(size_t)g * 512 + c + 256] = f2bf(a1);
    s3[(size_t)g * 512 + c]       = f2bf(b0);
    s3[(size_t)g * 512 + c + 256] = f2bf(b1);
}

// b''[j] = edge_b0[j] + sum_c emb_b1[c]*W3[c][j];  bsum[j] = emb_b1[j]+edge_b1[j]
__global__ __launch_bounds__(256)
void biasfold(const float* __restrict__ edge_b0, const float* __restrict__ emb_b1,
              const float* __restrict__ w3, const float* __restrict__ edge_b1,
              float* __restrict__ bpp, float* __restrict__ bsum)
{
    const int j = blockIdx.x * 256 + threadIdx.x;
    if (j >= 512) return;
    float a = edge_b0[j];
    for (int c = 0; c < 512; ++c) a += emb_b1[c] * w3[(size_t)c * 512 + j];
    bpp[j]  = a;
    bsum[j] = emb_b1[j] + edge_b1[j];
}

extern "C" void kernel_launch(void* const* d_in, const int* in_sizes, int n_in,
                              void* d_out, int out_size, void* d_ws, size_t ws_size,
                              hipStream_t stream)
{
    const float* mesh    = (const float*)d_in[0];
    const float* gridf   = (const float*)d_in[1];
    const float* attrs   = (const float*)d_in[2];
    const int*   esrc    = (const int*)d_in[3];
    const int*   edst    = (const int*)d_in[4];
    const float* emb_w0  = (const float*)d_in[5];
    const float* emb_b0  = (const float*)d_in[6];
    const float* emb_w1  = (const float*)d_in[7];
    const float* emb_b1  = (const float*)d_in[8];
    const float* edge_w0 = (const float*)d_in[9];
    const float* edge_b0 = (const float*)d_in[10];
    const float* edge_w1 = (const float*)d_in[11];
    const float* edge_b1 = (const float*)d_in[12];
    const float* node_w0 = (const float*)d_in[13];
    const float* node_b0 = (const float*)d_in[14];
    const float* node_w1 = (const float*)d_in[15];
    const float* node_b1 = (const float*)d_in[16];
    const float* out_w0  = (const float*)d_in[17];
    const float* out_b0  = (const float*)d_in[18];
    const float* out_w1  = (const float*)d_in[19];
    const float* out_b1  = (const float*)d_in[20];

    // ws (534 MB baseline footprint):
    //  region1 (200 MB): h1 (live thru G3''+segsum2) -> aggB -> g2
    //  region2 (200 MB): hb3 -> hb (G5/G7 outputs)
    //  r3 (133 MB): gridP (66.7) | meshP (10.5)  [both dead after G3''] ->
    //               s1 (66.7) | s3 (66.7)        [dead after GA] ->
    //               out_w1T at base (read by G8)
    // d_out (122.8 MB) scratch until G8 (~100 MB used), overwritten by G8.
    char* ws = (char*)d_ws;
    unsigned short* h1  = (unsigned short*)ws;
    unsigned short* hb  = (unsigned short*)(ws + (size_t)NE * 512 * 2);
    char*           r3  = ws + (size_t)2 * NE * 512 * 2;   // 133,447,680 B
    unsigned short* aggB = h1;                             // after h1 dead
    unsigned short* g2   = h1;                             // after aggB dead
    unsigned short* gridP = (unsigned short*)r3;
    unsigned short* meshP = (unsigned short*)(r3 + 66723840);
    unsigned short* s1    = (unsigned short*)r3;           // after gridP dead
    unsigned short* s3    = (unsigned short*)(r3 + 66723840); // after meshP dead
    unsigned short* out_w1T = (unsigned short*)r3;         // after s1 dead

    char* sc = (char*)d_out;                               // scratch until G8
    unsigned short* BwGA     = (unsigned short*)sc;                 // [512][1024]
    unsigned short* node_w0T = (unsigned short*)(sc +  1048576);    // [512][1024]
    unsigned short* node_w1T = (unsigned short*)(sc +  2097152);    // [512][512]
    unsigned short* out_w0T  = (unsigned short*)(sc +  2621440);    // [512][512]
    unsigned short* W1T      = (unsigned short*)(sc +  3145728);    // [512][512]
    unsigned short* W2T      = (unsigned short*)(sc +  3670016);    // [512][512]
    unsigned short* W3T      = (unsigned short*)(sc +  4194304);    // [512][512]
    unsigned short* WpT      = (unsigned short*)(sc +  4718592);    // [512][512]
    unsigned short* emb_w1b  = (unsigned short*)(sc +  5242880);    // [512][512]
    unsigned short* meshB    = (unsigned short*)(sc +  5767168);    // NM*512
    unsigned short* gridB    = (unsigned short*)(sc + 16254976);    // NG*512
    unsigned*       fillA    = (unsigned*)      (sc + 82978816);    // NG u32
    float*          zbias    = (float*)         (sc + 83239456);    // 512 f32
    float*          bpp      = (float*)         (sc + 83241504);    // 512 f32
    float*          bsum     = (float*)         (sc + 83243552);    // 512 f32
    unsigned*       slots    = (unsigned*)      (sc + 83245600);    // NG*64 u32

    // zero fillA + zbias (contiguous)
    hipMemsetAsync(fillA, 0, 260640 + 2048, stream);

    dim3 blk(256);
    // weight prep (all into d_out scratch)
    { dim3 g( 8, 8); wconv<<<g, blk, 0, stream>>>(edge_w0,                      W1T, 512, 512, 512,  512); }
    { dim3 g( 8, 8); wconv<<<g, blk, 0, stream>>>(edge_w0 + (size_t) 512 * 512, W2T, 512, 512, 512,  512); }
    { dim3 g( 8, 8); wconv<<<g, blk, 0, stream>>>(edge_w0 + (size_t)1024 * 512, W3T, 512, 512, 512,  512); }
    { dim3 g( 8, 8); wconv<<<g, blk, 0, stream>>>(emb_w1,  BwGA,       512, 512, 512, 1024); }
    { dim3 g( 8, 8); wconv<<<g, blk, 0, stream>>>(edge_w1, BwGA + 512, 512, 512, 512, 1024); }
    { dim3 g(16, 8); wconv<<<g, blk, 0, stream>>>(node_w0, node_w0T, 1024, 512, 512, 1024); }
    { dim3 g( 8, 8); wconv<<<g, blk, 0, stream>>>(node_w1, node_w1T,  512, 512, 512,  512); }
    { dim3 g( 8, 8); wconv<<<g, blk, 0, stream>>>(out_w0,  out_w0T,   512, 512, 512,  512); }
    cvtb<<<128, blk, 0, stream>>>(emb_w1, emb_w1b, 512 * 512 / 8);
    cvtb<<<(int)(((long long)NM * 512 / 8 + 255) / 256), blk, 0, stream>>>(mesh,  meshB, (long long)NM * 512 / 8);
    cvtb<<<(int)(((long long)NG * 512 / 8 + 255) / 256), blk, 0, stream>>>(gridf, gridB, (long long)NG * 512 / 8);
    fillslots<<<(NE + 255) / 256, blk, 0, stream>>>(edst, fillA, slots);
    biasfold<<<2, blk, 0, stream>>>(edge_b0, emb_b1, edge_w0 + (size_t)1024 * 512, edge_b1, bpp, bsum);

    const int nwgE = 4 * ((NE + 127) / 128);   // 6112 (div 8)
    const int nwgG = 4 * ((NG + 127) / 128);   // 2040 (div 8)
    const int nwgM = 4 * ((NM + 127) / 128);   // 324

    // W' = emb_w1 @ W3, stored transposed: WpT[n][k] = W'[k][n]
    gemm128<A_PLAIN, E_BIAS_BF16><<<16, blk, 0, stream>>>(W3T, nullptr, emb_w1b, zbias,
        512, 512, 512, 512, nullptr, nullptr, nullptr, nullptr, nullptr, nullptr, WpT, nullptr);
    // meshP = meshB @ W1
    gemm128<A_PLAIN, E_BIAS_BF16><<<nwgM, blk, 0, stream>>>(meshB, nullptr, W1T, zbias,
        NM, 512, 512, 512, nullptr, nullptr, nullptr, nullptr, nullptr, nullptr, meshP, nullptr);
    // gridP = gridB @ W2 + b''  (b'' folded here: each edge adds gridP[dst] once)
    gemm128<A_PLAIN, E_BIAS_BF16><<<nwgG, blk, 0, stream>>>(gridB, nullptr, W2T, bpp,
        NG, 512, 512, 512, nullptr, nullptr, nullptr, nullptr, nullptr, nullptr, gridP, nullptr);

    // L1: h1 = silu(attrs @ emb_w0 + b)
    embed_l1<<<(int)(((long long)NE * 512 + 255) / 256), blk, 0, stream>>>(attrs, emb_w0, emb_b0, h1);

    // G3'': hb3 = silu(h1@W' + meshP[src] + gridP[dst])   (K=512, gather epilogue)
    gemm128<A_PLAIN, E_EDGE_SILU><<<nwgE, blk, 0, stream>>>(h1, nullptr, WpT, zbias,
        NE, 512, 512, 512, nullptr, esrc, edst, nullptr, meshP, gridP, hb, nullptr);
    // fused segment-sums: s1 = seg(h1), s3 = seg(hb3)  (overwrites gridP/meshP)
    segsum2<<<NG, blk, 0, stream>>>(h1, hb, fillA, slots, s1, s3);
    // GA: aggB = [s1|s3] @ [emb_w1; edge_w1] + deg*(emb_b1+edge_b1)   (K=1024)
    gemm128<A_NODE, E_AGG_BF16><<<nwgG, blk, 0, stream>>>(s1, s3, BwGA, bsum,
        NG, 512, 1024, 512, nullptr, nullptr, nullptr, fillA, nullptr, nullptr, aggB, nullptr);
    // s1/s3 dead -> out_w1T into r3 for G8
    { dim3 g( 8, 8); wconv<<<g, blk, 0, stream>>>(out_w1, out_w1T, 512, 471, 512, 512); }
    // G5: hb = silu([gridB | aggB] @ node_w0 + b)
    gemm128<A_NODE, E_SILU_BF16><<<nwgG, blk, 0, stream>>>(gridB, aggB, node_w0T, node_b0,
        NG, 512, 1024, 512, nullptr, nullptr, nullptr, nullptr, nullptr, nullptr, hb, nullptr);
    // G6: g2 = grid + hb @ node_w1 + b
    gemm128<A_PLAIN, E_RESID_BF16><<<nwgG, blk, 0, stream>>>(hb, nullptr, node_w1T, node_b1,
        NG, 512, 512, 512, gridf, nullptr, nullptr, nullptr, nullptr, nullptr, g2, nullptr);
    // G7: hb = silu(g2 @ out_w0 + b)
    gemm128<A_PLAIN, E_SILU_BF16><<<nwgG, blk, 0, stream>>>(g2, nullptr, out_w0T, out_b0,
        NG, 512, 512, 512, nullptr, nullptr, nullptr, nullptr, nullptr, nullptr, hb, nullptr);
    // G8: out = hb @ out_w1 + b (fp32, N=471; overwrites all d_out scratch)
    gemm128<A_PLAIN, E_OUT_F32><<<nwgG, blk, 0, stream>>>(hb, nullptr, out_w1T, out_b1,
        NG, NOUT, 512, NOUT, nullptr, nullptr, nullptr, nullptr, nullptr, nullptr, nullptr, (float*)d_out);
}

// Round 14
// 1681.280 us; speedup vs baseline: 1.1303x; 1.1303x over previous
//
#include <hip/hip_runtime.h>
#include <stdint.h>

#define NE 195480
#define NM 10242
#define NG 65160
#define DD 512
#define NOUT 471

typedef __attribute__((ext_vector_type(8))) short bf16x8;
typedef __attribute__((ext_vector_type(4))) float f32x4;
typedef __attribute__((ext_vector_type(8))) unsigned short ushort8;

__device__ __forceinline__ float bf2f(unsigned short u) {
    union { unsigned int i; float f; } v; v.i = ((unsigned int)u) << 16; return v.f;
}
__device__ __forceinline__ unsigned short f2bf(float f) {
    union { float f; unsigned int u; } v; v.f = f;
    unsigned int x = v.u;
    return (unsigned short)((x + 0x7fffu + ((x >> 16) & 1u)) >> 16);
}
__device__ __forceinline__ float silu_f(float x) { return x / (1.f + __expf(-x)); }

__device__ __forceinline__ ushort8 cvt8(const float* __restrict__ p) {
    const f32x4 lo = *(const f32x4*)p;
    const f32x4 hi = *(const f32x4*)(p + 4);
    ushort8 r;
    #pragma unroll
    for (int j = 0; j < 4; ++j) { r[j] = f2bf(lo[j]); r[j + 4] = f2bf(hi[j]); }
    return r;
}

// async global->LDS, 16B per lane. LDS dest lane-linear; global src per-lane.
__device__ __forceinline__ void gl_lds16(const unsigned short* g, unsigned short* l) {
    __builtin_amdgcn_global_load_lds(
        (const __attribute__((address_space(1))) unsigned int*)g,
        (__attribute__((address_space(3))) unsigned int*)l, 16, 0, 0);
}

enum { A_PLAIN = 0, A_SEG = 1 };
enum { E_BIAS_BF16 = 0, E_SILU_BF16 = 1, E_AGGSILU = 2, E_OUT_F32 = 3 };

// C = epilogue(A @ B + ...), 128x128 tile, BK=64, 4 waves (2x2).
// 1D grid + bijective chunked XCD swizzle (verified R11: 3.2x FETCH cut).
// m97-style global_load_lds staging, source-chunk swizzle, 0 bank conflicts.
// R14: gather epilogues removed (R13 lesson: 116 VGPR + latency-bound scalar
// gathers at 22% occ cost more than the MFMA they save). Epilogues are pure
// vector math; gathers live in the coalesced esilu kernel.
// A_SEG: A = [Asrc | Asrc2 | Asrc3], each stride-512 bf16, selected by k0.
// E_AGGSILU: v = silu(acc + bias[j] + deg[row]*bias2[j])  (GA folded into G5).
template<int AMODE, int EPI>
__global__ __launch_bounds__(256)
void gemm128(const unsigned short* __restrict__ Asrc,
             const unsigned short* __restrict__ Asrc2,
             const unsigned short* __restrict__ Asrc3,
             const unsigned short* __restrict__ Bw,     // bf16 [512][K]
             const float* __restrict__ bias,
             const float* __restrict__ bias2,           // E_AGGSILU deg-scaled
             int M, int N, int K, int ldOut,
             const unsigned* __restrict__ degA,
             unsigned short* __restrict__ outB,
             float* __restrict__ outF)
{
    __shared__ unsigned short As[128 * 64];
    __shared__ unsigned short Bs[128 * 64];

    const int tid  = threadIdx.x;
    const int nwg  = gridDim.x;
    int orig = blockIdx.x;
    if ((nwg & 7) == 0) {                       // bijective chunked XCD swizzle
        const int q = nwg >> 3;
        orig = (blockIdx.x & 7) * q + (blockIdx.x >> 3);
    }
    const int bn = orig & 3;
    const int bm = orig >> 2;

    const int w    = tid >> 6;
    const int lane = tid & 63;
    const int quad = lane >> 4;
    const int ln   = lane & 15;
    const int wr   = w >> 1;
    const int wc   = w & 1;

    const int srow = tid >> 3;    // 0..31
    const int sc   = tid & 7;     // 0..7
    const int ck   = (sc ^ (srow & 7)) * 8;   // swizzled source chunk (elems)

    int arowc[4];
    #pragma unroll
    for (int i = 0; i < 4; ++i) {
        int r = bm * 128 + i * 32 + srow;
        arowc[i] = (r < M) ? r : (M - 1);
    }

    f32x4 acc[4][4] = {};

    for (int k0 = 0; k0 < K; k0 += 64) {
        __syncthreads();   // previous compute done reading LDS
        #pragma unroll
        for (int i = 0; i < 4; ++i) {
            const int row = i * 32 + srow;
            const unsigned short* ga;
            if (AMODE == A_PLAIN) {
                ga = Asrc + (size_t)arowc[i] * K + k0 + ck;
            } else { // A_SEG: stride-512 segments
                if (k0 < 512)       ga = Asrc  + (size_t)arowc[i] * 512 + k0 + ck;
                else if (k0 < 1024) ga = Asrc2 + (size_t)arowc[i] * 512 + (k0 - 512) + ck;
                else                ga = Asrc3 + (size_t)arowc[i] * 512 + (k0 - 1024) + ck;
            }
            gl_lds16(ga, As + i * 2048 + tid * 8);
            gl_lds16(Bw + (size_t)(bn * 128 + row) * K + k0 + ck, Bs + i * 2048 + tid * 8);
        }
        __syncthreads();   // vmcnt(0) drained before barrier -> staged

        #pragma unroll
        for (int kt = 0; kt < 2; ++kt) {
            bf16x8 af[4], bfv[4];
            #pragma unroll
            for (int m = 0; m < 4; ++m) {
                const int r = wr * 64 + m * 16 + ln;
                af[m] = *(const bf16x8*)(As + r * 64 + (((kt * 4 + quad) ^ (r & 7)) * 8));
            }
            #pragma unroll
            for (int n = 0; n < 4; ++n) {
                const int r = wc * 64 + n * 16 + ln;
                bfv[n] = *(const bf16x8*)(Bs + r * 64 + (((kt * 4 + quad) ^ (r & 7)) * 8));
            }
            #pragma unroll
            for (int m = 0; m < 4; ++m)
                #pragma unroll
                for (int n = 0; n < 4; ++n)
                    acc[m][n] = __builtin_amdgcn_mfma_f32_16x16x32_bf16(af[m], bfv[n], acc[m][n], 0, 0, 0);
        }
    }

    // ---- epilogue (pure vector math; no gathers) ----
    int colg[4]; float bcol[4], bcol2[4]; bool cok[4];
    #pragma unroll
    for (int n = 0; n < 4; ++n) {
        colg[n] = bn * 128 + wc * 64 + n * 16 + ln;
        cok[n]  = (colg[n] < N);
        bcol[n] = cok[n] ? bias[colg[n]] : 0.f;
        bcol2[n] = (EPI == E_AGGSILU && cok[n]) ? bias2[colg[n]] : 0.f;
    }
    #pragma unroll
    for (int m = 0; m < 4; ++m) {
        #pragma unroll
        for (int r = 0; r < 4; ++r) {
            const int row_g = bm * 128 + wr * 64 + m * 16 + quad * 4 + r;
            if (row_g >= M) continue;
            const float deg = (EPI == E_AGGSILU) ? (float)degA[row_g] : 0.f;
            #pragma unroll
            for (int n = 0; n < 4; ++n) {
                if (!cok[n]) continue;
                float v = acc[m][n][r] + bcol[n];
                if (EPI == E_BIAS_BF16) {
                    outB[(size_t)row_g * ldOut + colg[n]] = f2bf(v);
                } else if (EPI == E_SILU_BF16) {
                    outB[(size_t)row_g * ldOut + colg[n]] = f2bf(silu_f(v));
                } else if (EPI == E_AGGSILU) {
                    outB[(size_t)row_g * ldOut + colg[n]] = f2bf(silu_f(v + deg * bcol2[n]));
                } else { // E_OUT_F32
                    outF[(size_t)row_g * N + colg[n]] = v;
                }
            }
        }
    }
}

// Transpose-convert: w f32 [K][N] -> wT bf16 [Npad][K-slice], row stride ldT.
__global__ __launch_bounds__(256)
void wconv(const float* __restrict__ w, unsigned short* __restrict__ wT,
           int K, int N, int Npad, int ldT)
{
    __shared__ float t[64][65];
    const int tid = threadIdx.x;
    const int bk = blockIdx.x * 64, bn = blockIdx.y * 64;
    const int cc = tid & 63, rr = tid >> 6;
    #pragma unroll
    for (int i = 0; i < 16; ++i) {
        const int k = rr + i * 4;
        float v = 0.f;
        if (bk + k < K && bn + cc < N) v = w[(size_t)(bk + k) * N + bn + cc];
        t[k][cc] = v;
    }
    __syncthreads();
    #pragma unroll
    for (int i = 0; i < 16; ++i) {
        const int n = rr + i * 4;
        if (bn + n < Npad && bk + cc < K)
            wT[(size_t)(bn + n) * ldT + bk + cc] = f2bf(t[cc][n]);
    }
}

// flat f32 -> bf16 convert, 8 elems/thread
__global__ __launch_bounds__(256)
void cvtb(const float* __restrict__ in, unsigned short* __restrict__ out, long long n8)
{
    const long long i = (long long)blockIdx.x * 256 + threadIdx.x;
    if (i >= n8) return;
    *(ushort8*)(out + i * 8) = cvt8(in + i * 8);
}

// h1 = silu(attrs @ emb_w0 + emb_b0), K=4
__global__ __launch_bounds__(256)
void embed_l1(const float* __restrict__ attrs,
              const float* __restrict__ w0,
              const float* __restrict__ b0,
              unsigned short* __restrict__ h)
{
    const long long idx = (long long)blockIdx.x * 256 + threadIdx.x;
    if (idx >= (long long)NE * 512) return;
    const int row = (int)(idx >> 9);
    const int c = (int)(idx & 511);
    float acc = b0[c];
    #pragma unroll
    for (int k = 0; k < 4; ++k)
        acc += attrs[row * 4 + k] * w0[k * 512 + c];
    h[idx] = f2bf(silu_f(acc));
}

// hb[row] = silu(z3[row] + meshP[esrc[row]] + gridP[edst[row]])  in-place.
// 4 rows/block; per row: 3x 1KB coalesced ushort8 reads + 1KB write.
__global__ __launch_bounds__(256)
void esilu(unsigned short* __restrict__ z,
           const unsigned short* __restrict__ mP,
           const unsigned short* __restrict__ gP,
           const int* __restrict__ esrc,
           const int* __restrict__ edst)
{
    const int row = blockIdx.x * 4 + (threadIdx.x >> 6);
    if (row >= NE) return;
    const int l8 = (threadIdx.x & 63) * 8;
    const int se = esrc[row], de = edst[row];
    ushort8 a = *(const ushort8*)(z  + (size_t)row * 512 + l8);
    ushort8 b = *(const ushort8*)(mP + (size_t)se  * 512 + l8);
    ushort8 c = *(const ushort8*)(gP + (size_t)de  * 512 + l8);
    ushort8 o;
    #pragma unroll
    for (int j = 0; j < 8; ++j)
        o[j] = f2bf(silu_f(bf2f(a[j]) + bf2f(b[j]) + bf2f(c[j])));
    *(ushort8*)(z + (size_t)row * 512 + l8) = o;
}

// Per-dst-node slot lists: fill[d] counter + slots[d][0..63] edge ids.
__global__ __launch_bounds__(256)
void fillslots(const int* __restrict__ edst, unsigned* __restrict__ fill,
               unsigned* __restrict__ slots)
{
    const int i = blockIdx.x * 256 + threadIdx.x;
    if (i >= NE) return;
    const int d = edst[i];
    const unsigned p = atomicAdd(&fill[d], 1u);
    if (p < 64u) slots[(size_t)d * 64 + p] = (unsigned)i;
}

// Fused segment-sums of BOTH h1 and hb3 (bf16 rows, f32 accum).
__global__ __launch_bounds__(256)
void segsum2(const unsigned short* __restrict__ h1,
             const unsigned short* __restrict__ h3,
             const unsigned* __restrict__ fill,
             const unsigned* __restrict__ slots,
             unsigned short* __restrict__ s1,
             unsigned short* __restrict__ s3)
{
    const int g = blockIdx.x;
    const int c = threadIdx.x;
    unsigned deg = fill[g]; if (deg > 64u) deg = 64u;
    float a0 = 0.f, a1 = 0.f, b0 = 0.f, b1 = 0.f;
    for (unsigned j = 0; j < deg; ++j) {
        const size_t row = (size_t)slots[(size_t)g * 64 + j] * 512;
        a0 += bf2f(h1[row + c]);
        a1 += bf2f(h1[row + c + 256]);
        b0 += bf2f(h3[row + c]);
        b1 += bf2f(h3[row + c + 256]);
    }
    s1[(size_t)g * 512 + c]       = f2bf(a0);
    s1[(size_t)g * 512 + c + 256] = f2bf(a1);
    s3[(size_t)g * 512 + c]       = f2bf(b0);
    s3[(size_t)g * 512 + c + 256] = f2bf(b1);
}

// out[j] = base[j] + sum_k (v1[k] + v2[k]) * W[k*512 + j]   (v2 optional)
__global__ __launch_bounds__(256)
void vmb(const float* __restrict__ base, const float* __restrict__ v1,
         const float* __restrict__ v2, const float* __restrict__ W,
         float* __restrict__ out)
{
    const int j = blockIdx.x * 256 + threadIdx.x;
    if (j >= 512) return;
    float a = base[j];
    for (int k = 0; k < 512; ++k) {
        float vk = v1[k] + (v2 ? v2[k] : 0.f);
        a += vk * W[(size_t)k * 512 + j];
    }
    out[j] = a;
}

extern "C" void kernel_launch(void* const* d_in, const int* in_sizes, int n_in,
                              void* d_out, int out_size, void* d_ws, size_t ws_size,
                              hipStream_t stream)
{
    const float* mesh    = (const float*)d_in[0];
    const float* gridf   = (const float*)d_in[1];
    const float* attrs   = (const float*)d_in[2];
    const int*   esrc    = (const int*)d_in[3];
    const int*   edst    = (const int*)d_in[4];
    const float* emb_w0  = (const float*)d_in[5];
    const float* emb_b0  = (const float*)d_in[6];
    const float* emb_w1  = (const float*)d_in[7];
    const float* emb_b1  = (const float*)d_in[8];
    const float* edge_w0 = (const float*)d_in[9];
    const float* edge_b0 = (const float*)d_in[10];
    const float* edge_w1 = (const float*)d_in[11];
    const float* edge_b1 = (const float*)d_in[12];
    const float* node_w0 = (const float*)d_in[13];
    const float* node_b0 = (const float*)d_in[14];
    const float* node_w1 = (const float*)d_in[15];
    const float* node_b1 = (const float*)d_in[16];
    const float* out_w0  = (const float*)d_in[17];
    const float* out_b0  = (const float*)d_in[18];
    const float* out_w1  = (const float*)d_in[19];
    const float* out_b1  = (const float*)d_in[20];

    // ws (534 MB baseline footprint):
    //  region1 (200 MB): h1 (live thru segsum2) -> hb5 (G5' out)
    //  region2 (200 MB): z3 -> hb3 (esilu in-place) -> hb7 (G7' out)
    //  r3 (133 MB): gridP(66.7)|meshP(10.5) -> s1|s3 -> out_w1T at base
    // d_out (122.8 MB) scratch until G8 (~101 MB used), overwritten by G8.
    char* ws = (char*)d_ws;
    unsigned short* h1  = (unsigned short*)ws;
    unsigned short* hb  = (unsigned short*)(ws + (size_t)NE * 512 * 2);   // z3/hb3/hb7
    char*           r3  = ws + (size_t)2 * NE * 512 * 2;   // 133,447,680 B
    unsigned short* hb5 = h1;                              // after h1 dead
    unsigned short* gridP = (unsigned short*)r3;
    unsigned short* meshP = (unsigned short*)(r3 + 66723840);
    unsigned short* s1    = (unsigned short*)r3;              // over gridP
    unsigned short* s3    = (unsigned short*)(r3 + 66723840); // over meshP
    unsigned short* out_w1T = (unsigned short*)r3;            // after s1 dead

    char* sc = (char*)d_out;                               // scratch until G8
    unsigned short* BwG5     = (unsigned short*)sc;                 // [512][1536]
    unsigned short* BwG7     = (unsigned short*)(sc +  1572864);    // [512][1024]
    unsigned short* W1T      = (unsigned short*)(sc +  2621440);
    unsigned short* W2T      = (unsigned short*)(sc +  3145728);
    unsigned short* W3T      = (unsigned short*)(sc +  3670016);
    unsigned short* WpT      = (unsigned short*)(sc +  4194304);
    unsigned short* nw0bT    = (unsigned short*)(sc +  4718592);
    unsigned short* ow0T     = (unsigned short*)(sc +  5242880);
    unsigned short* emb_w1b  = (unsigned short*)(sc +  5767168);
    unsigned short* edge_w1b = (unsigned short*)(sc +  6291456);
    unsigned short* node_w1b = (unsigned short*)(sc +  6815744);
    unsigned short* meshB    = (unsigned short*)(sc +  7340032);    // NM*512
    unsigned short* gridB    = (unsigned short*)(sc + 17827840);    // NG*512
    unsigned*       fillA    = (unsigned*)      (sc + 84551680);
    float*          zbias    = (float*)         (sc + 84812320);
    float*          bpp      = (float*)         (sc + 84814368);
    float*          c5       = (float*)         (sc + 84816416);
    float*          b7       = (float*)         (sc + 84818464);
    unsigned*       slots    = (unsigned*)      (sc + 84820512);    // NG*64 u32

    // zero fillA + zbias (contiguous)
    hipMemsetAsync(fillA, 0, 260640 + 2048, stream);

    dim3 blk(256);
    // transposes / converts into d_out scratch
    { dim3 g(8, 8); wconv<<<g, blk, 0, stream>>>(edge_w0,                      W1T, 512, 512, 512,  512); }
    { dim3 g(8, 8); wconv<<<g, blk, 0, stream>>>(edge_w0 + (size_t) 512 * 512, W2T, 512, 512, 512,  512); }
    { dim3 g(8, 8); wconv<<<g, blk, 0, stream>>>(edge_w0 + (size_t)1024 * 512, W3T, 512, 512, 512,  512); }
    { dim3 g(8, 8); wconv<<<g, blk, 0, stream>>>(node_w0,                      BwG5, 512, 512, 512, 1536); }  // nw0a
    { dim3 g(8, 8); wconv<<<g, blk, 0, stream>>>(node_w0 + (size_t)512 * 512,  nw0bT, 512, 512, 512, 512); }
    { dim3 g(8, 8); wconv<<<g, blk, 0, stream>>>(out_w0,  ow0T, 512, 512, 512,  512); }
    { dim3 g(8, 8); wconv<<<g, blk, 0, stream>>>(out_w0,  BwG7, 512, 512, 512, 1024); }   // G7 cols 0:512
    cvtb<<<128, blk, 0, stream>>>(emb_w1,  emb_w1b,  512 * 512 / 8);
    cvtb<<<128, blk, 0, stream>>>(edge_w1, edge_w1b, 512 * 512 / 8);
    cvtb<<<128, blk, 0, stream>>>(node_w1, node_w1b, 512 * 512 / 8);
    cvtb<<<(int)(((long long)NM * 512 / 8 + 255) / 256), blk, 0, stream>>>(mesh,  meshB, (long long)NM * 512 / 8);
    cvtb<<<(int)(((long long)NG * 512 / 8 + 255) / 256), blk, 0, stream>>>(gridf, gridB, (long long)NG * 512 / 8);
    fillslots<<<(NE + 255) / 256, blk, 0, stream>>>(edst, fillA, slots);
    // bias folds: bpp = edge_b0 + emb_b1@W3 ; c5 = (emb_b1+edge_b1)@nw0b ; b7 = out_b0 + node_b1@out_w0
    vmb<<<2, blk, 0, stream>>>(edge_b0, emb_b1, nullptr, edge_w0 + (size_t)1024 * 512, bpp);
    vmb<<<2, blk, 0, stream>>>(zbias, emb_b1, edge_b1, node_w0 + (size_t)512 * 512, c5);
    vmb<<<2, blk, 0, stream>>>(out_b0, node_b1, nullptr, out_w0, b7);

    // composite weights (each stored transposed [n][k]):
    // WpT = (emb_w1@W3)^T ; U1=(emb_w1@nw0b)^T -> BwG5+512 ; U2=(edge_w1@nw0b)^T
    // -> BwG5+1024 ; U3=(node_w1@out_w0)^T -> BwG7+512
    gemm128<A_PLAIN, E_BIAS_BF16><<<16, blk, 0, stream>>>(W3T, nullptr, nullptr, emb_w1b, zbias, nullptr,
        512, 512, 512, 512, nullptr, WpT, nullptr);
    gemm128<A_PLAIN, E_BIAS_BF16><<<16, blk, 0, stream>>>(nw0bT, nullptr, nullptr, emb_w1b, zbias, nullptr,
        512, 512, 512, 1536, nullptr, BwG5 + 512, nullptr);
    gemm128<A_PLAIN, E_BIAS_BF16><<<16, blk, 0, stream>>>(nw0bT, nullptr, nullptr, edge_w1b, zbias, nullptr,
        512, 512, 512, 1536, nullptr, BwG5 + 1024, nullptr);
    gemm128<A_PLAIN, E_BIAS_BF16><<<16, blk, 0, stream>>>(ow0T, nullptr, nullptr, node_w1b, zbias, nullptr,
        512, 512, 512, 1024, nullptr, BwG7 + 512, nullptr);

    // L1: h1 = silu(attrs @ emb_w0 + b)
    embed_l1<<<(int)(((long long)NE * 512 + 255) / 256), blk, 0, stream>>>(attrs, emb_w0, emb_b0, h1);

    const int nwgE = 4 * ((NE + 127) / 128);   // 6112
    const int nwgG = 4 * ((NG + 127) / 128);   // 2040
    const int nwgM = 4 * ((NM + 127) / 128);   // 324

    // meshP = meshB @ W1 ; gridP = gridB @ W2 + b''
    gemm128<A_PLAIN, E_BIAS_BF16><<<nwgM, blk, 0, stream>>>(meshB, nullptr, nullptr, W1T, zbias, nullptr,
        NM, 512, 512, 512, nullptr, meshP, nullptr);
    gemm128<A_PLAIN, E_BIAS_BF16><<<nwgG, blk, 0, stream>>>(gridB, nullptr, nullptr, W2T, bpp, nullptr,
        NG, 512, 512, 512, nullptr, gridP, nullptr);

    // G3''': z3 = h1 @ W'   (clean K=512 GEMM, no gather epilogue)
    gemm128<A_PLAIN, E_BIAS_BF16><<<nwgE, blk, 0, stream>>>(h1, nullptr, nullptr, WpT, zbias, nullptr,
        NE, 512, 512, 512, nullptr, hb, nullptr);
    // hb3 = silu(z3 + meshP[src] + gridP[dst])  (coalesced row gathers)
    esilu<<<(NE + 3) / 4, blk, 0, stream>>>(hb, meshP, gridP, esrc, edst);
    // fused segment-sums: s1 = seg(h1), s3 = seg(hb3)  (overwrite gridP/meshP)
    segsum2<<<NG, blk, 0, stream>>>(h1, hb, fillA, slots, s1, s3);
    // G5': hb5 = silu([gridB|s1|s3] @ [nw0a;U1;U2] + node_b0 + deg*c5)  (K=1536)
    gemm128<A_SEG, E_AGGSILU><<<nwgG, blk, 0, stream>>>(gridB, s1, s3, BwG5, node_b0, c5,
        NG, 512, 1536, 512, fillA, hb5, nullptr);
    // s1/s3 dead -> out_w1T into r3 for G8
    { dim3 g(8, 8); wconv<<<g, blk, 0, stream>>>(out_w1, out_w1T, 512, 471, 512, 512); }
    // G7': hb7 = silu([gridB|hb5] @ [ow0;U3] + b7)  (K=1024; G6 folded in)
    gemm128<A_SEG, E_SILU_BF16><<<nwgG, blk, 0, stream>>>(gridB, hb5, nullptr, BwG7, b7, nullptr,
        NG, 512, 1024, 512, nullptr, hb, nullptr);
    // G8: out = hb7 @ out_w1 + b (fp32, N=471; overwrites all d_out scratch)
    gemm128<A_PLAIN, E_OUT_F32><<<nwgG, blk, 0, stream>>>(hb, nullptr, nullptr, out_w1T, out_b1, nullptr,
        NG, NOUT, 512, NOUT, nullptr, nullptr, (float*)d_out);
}

// Round 15
// 1482.359 us; speedup vs baseline: 1.2820x; 1.1342x over previous
//
#include <hip/hip_runtime.h>
#include <stdint.h>

#define NE 195480
#define NM 10242
#define NG 65160
#define DD 512
#define NOUT 471

typedef __attribute__((ext_vector_type(8))) short bf16x8;
typedef __attribute__((ext_vector_type(4))) float f32x4;
typedef __attribute__((ext_vector_type(8))) unsigned short ushort8;

__device__ __forceinline__ float bf2f(unsigned short u) {
    union { unsigned int i; float f; } v; v.i = ((unsigned int)u) << 16; return v.f;
}
__device__ __forceinline__ unsigned short f2bf(float f) {
    union { float f; unsigned int u; } v; v.f = f;
    unsigned int x = v.u;
    return (unsigned short)((x + 0x7fffu + ((x >> 16) & 1u)) >> 16);
}
__device__ __forceinline__ float silu_f(float x) { return x / (1.f + __expf(-x)); }

__device__ __forceinline__ ushort8 cvt8(const float* __restrict__ p) {
    const f32x4 lo = *(const f32x4*)p;
    const f32x4 hi = *(const f32x4*)(p + 4);
    ushort8 r;
    #pragma unroll
    for (int j = 0; j < 4; ++j) { r[j] = f2bf(lo[j]); r[j + 4] = f2bf(hi[j]); }
    return r;
}

// async global->LDS, 16B per lane. LDS dest lane-linear; global src per-lane.
__device__ __forceinline__ void gl_lds16(const unsigned short* g, unsigned short* l) {
    __builtin_amdgcn_global_load_lds(
        (const __attribute__((address_space(1))) unsigned int*)g,
        (__attribute__((address_space(3))) unsigned int*)l, 16, 0, 0);
}

enum { A_PLAIN = 0, A_SEG = 1 };
enum { E_BIAS_BF16 = 0, E_SILU_BF16 = 1, E_AGGSILU = 2, E_OUT_F32 = 3 };

// C = epilogue(A @ B + ...), 128x128 tile, BK=64, 4 waves (2x2).
// 1D grid + bijective chunked XCD swizzle (R11: 3.2x FETCH cut verified).
// m97-style global_load_lds staging, source-chunk swizzle, 0 bank conflicts.
// Epilogues are pure vector math (R13 lesson: no gathers here).
template<int AMODE, int EPI>
__global__ __launch_bounds__(256)
void gemm128(const unsigned short* __restrict__ Asrc,
             const unsigned short* __restrict__ Asrc2,
             const unsigned short* __restrict__ Asrc3,
             const unsigned short* __restrict__ Bw,     // bf16 [512][K]
             const float* __restrict__ bias,
             const float* __restrict__ bias2,           // E_AGGSILU deg-scaled
             int M, int N, int K, int ldOut,
             const unsigned* __restrict__ degA,
             unsigned short* __restrict__ outB,
             float* __restrict__ outF)
{
    __shared__ unsigned short As[128 * 64];
    __shared__ unsigned short Bs[128 * 64];

    const int tid  = threadIdx.x;
    const int nwg  = gridDim.x;
    int orig = blockIdx.x;
    if ((nwg & 7) == 0) {                       // bijective chunked XCD swizzle
        const int q = nwg >> 3;
        orig = (blockIdx.x & 7) * q + (blockIdx.x >> 3);
    }
    const int bn = orig & 3;
    const int bm = orig >> 2;

    const int w    = tid >> 6;
    const int lane = tid & 63;
    const int quad = lane >> 4;
    const int ln   = lane & 15;
    const int wr   = w >> 1;
    const int wc   = w & 1;

    const int srow = tid >> 3;    // 0..31
    const int sc   = tid & 7;     // 0..7
    const int ck   = (sc ^ (srow & 7)) * 8;   // swizzled source chunk (elems)

    int arowc[4];
    #pragma unroll
    for (int i = 0; i < 4; ++i) {
        int r = bm * 128 + i * 32 + srow;
        arowc[i] = (r < M) ? r : (M - 1);
    }

    f32x4 acc[4][4] = {};

    for (int k0 = 0; k0 < K; k0 += 64) {
        __syncthreads();   // previous compute done reading LDS
        #pragma unroll
        for (int i = 0; i < 4; ++i) {
            const int row = i * 32 + srow;
            const unsigned short* ga;
            if (AMODE == A_PLAIN) {
                ga = Asrc + (size_t)arowc[i] * K + k0 + ck;
            } else { // A_SEG: stride-512 segments
                if (k0 < 512)       ga = Asrc  + (size_t)arowc[i] * 512 + k0 + ck;
                else if (k0 < 1024) ga = Asrc2 + (size_t)arowc[i] * 512 + (k0 - 512) + ck;
                else                ga = Asrc3 + (size_t)arowc[i] * 512 + (k0 - 1024) + ck;
            }
            gl_lds16(ga, As + i * 2048 + tid * 8);
            gl_lds16(Bw + (size_t)(bn * 128 + row) * K + k0 + ck, Bs + i * 2048 + tid * 8);
        }
        __syncthreads();   // vmcnt(0) drained before barrier -> staged

        #pragma unroll
        for (int kt = 0; kt < 2; ++kt) {
            bf16x8 af[4], bfv[4];
            #pragma unroll
            for (int m = 0; m < 4; ++m) {
                const int r = wr * 64 + m * 16 + ln;
                af[m] = *(const bf16x8*)(As + r * 64 + (((kt * 4 + quad) ^ (r & 7)) * 8));
            }
            #pragma unroll
            for (int n = 0; n < 4; ++n) {
                const int r = wc * 64 + n * 16 + ln;
                bfv[n] = *(const bf16x8*)(Bs + r * 64 + (((kt * 4 + quad) ^ (r & 7)) * 8));
            }
            #pragma unroll
            for (int m = 0; m < 4; ++m)
                #pragma unroll
                for (int n = 0; n < 4; ++n)
                    acc[m][n] = __builtin_amdgcn_mfma_f32_16x16x32_bf16(af[m], bfv[n], acc[m][n], 0, 0, 0);
        }
    }

    // ---- epilogue (pure vector math; no gathers) ----
    int colg[4]; float bcol[4], bcol2[4]; bool cok[4];
    #pragma unroll
    for (int n = 0; n < 4; ++n) {
        colg[n] = bn * 128 + wc * 64 + n * 16 + ln;
        cok[n]  = (colg[n] < N);
        bcol[n] = cok[n] ? bias[colg[n]] : 0.f;
        bcol2[n] = (EPI == E_AGGSILU && cok[n]) ? bias2[colg[n]] : 0.f;
    }
    #pragma unroll
    for (int m = 0; m < 4; ++m) {
        #pragma unroll
        for (int r = 0; r < 4; ++r) {
            const int row_g = bm * 128 + wr * 64 + m * 16 + quad * 4 + r;
            if (row_g >= M) continue;
            const float deg = (EPI == E_AGGSILU) ? (float)degA[row_g] : 0.f;
            #pragma unroll
            for (int n = 0; n < 4; ++n) {
                if (!cok[n]) continue;
                float v = acc[m][n][r] + bcol[n];
                if (EPI == E_BIAS_BF16) {
                    outB[(size_t)row_g * ldOut + colg[n]] = f2bf(v);
                } else if (EPI == E_SILU_BF16) {
                    outB[(size_t)row_g * ldOut + colg[n]] = f2bf(silu_f(v));
                } else if (EPI == E_AGGSILU) {
                    outB[(size_t)row_g * ldOut + colg[n]] = f2bf(silu_f(v + deg * bcol2[n]));
                } else { // E_OUT_F32
                    outF[(size_t)row_g * N + colg[n]] = v;
                }
            }
        }
    }
}

// Transpose-convert: w f32 [K][N] -> wT bf16 [Npad][K-slice], row stride ldT.
__global__ __launch_bounds__(256)
void wconv(const float* __restrict__ w, unsigned short* __restrict__ wT,
           int K, int N, int Npad, int ldT)
{
    __shared__ float t[64][65];
    const int tid = threadIdx.x;
    const int bk = blockIdx.x * 64, bn = blockIdx.y * 64;
    const int cc = tid & 63, rr = tid >> 6;
    #pragma unroll
    for (int i = 0; i < 16; ++i) {
        const int k = rr + i * 4;
        float v = 0.f;
        if (bk + k < K && bn + cc < N) v = w[(size_t)(bk + k) * N + bn + cc];
        t[k][cc] = v;
    }
    __syncthreads();
    #pragma unroll
    for (int i = 0; i < 16; ++i) {
        const int n = rr + i * 4;
        if (bn + n < Npad && bk + cc < K)
            wT[(size_t)(bn + n) * ldT + bk + cc] = f2bf(t[cc][n]);
    }
}

// flat f32 -> bf16 convert, 8 elems/thread
__global__ __launch_bounds__(256)
void cvtb(const float* __restrict__ in, unsigned short* __restrict__ out, long long n8)
{
    const long long i = (long long)blockIdx.x * 256 + threadIdx.x;
    if (i >= n8) return;
    *(ushort8*)(out + i * 8) = cvt8(in + i * 8);
}

// h1 = silu(attrs @ emb_w0 + emb_b0), K=4 — vectorized, 8 cols/thread.
__global__ __launch_bounds__(256)
void embed_l1(const float* __restrict__ attrs,
              const float* __restrict__ w0,
              const float* __restrict__ b0,
              unsigned short* __restrict__ h)
{
    const long long i = (long long)blockIdx.x * 256 + threadIdx.x;
    if (i >= (long long)NE * 64) return;
    const int row = (int)(i >> 6);
    const int c8  = (int)(i & 63) * 8;
    const float t0 = attrs[row * 4], t1 = attrs[row * 4 + 1];
    const float t2 = attrs[row * 4 + 2], t3 = attrs[row * 4 + 3];
    ushort8 o;
    #pragma unroll
    for (int j = 0; j < 8; ++j) {
        const int c = c8 + j;
        float a = b0[c] + t0 * w0[c] + t1 * w0[512 + c]
                + t2 * w0[1024 + c] + t3 * w0[1536 + c];
        o[j] = f2bf(silu_f(a));
    }
    *(ushort8*)(h + (size_t)row * 512 + c8) = o;
}

// Per-dst-node slot lists: fill[d] counter + slots[d][0..63] edge ids.
__global__ __launch_bounds__(256)
void fillslots(const int* __restrict__ edst, unsigned* __restrict__ fill,
               unsigned* __restrict__ slots)
{
    const int i = blockIdx.x * 256 + threadIdx.x;
    if (i >= NE) return;
    const int d = edst[i];
    const unsigned p = atomicAdd(&fill[d], 1u);
    if (p < 64u) slots[(size_t)d * 64 + p] = (unsigned)i;
}

// Fully fused edge-finish + segment-sum (R15):
//   s1[g] = sum_{e: dst=g} h1[e]            (h1 recomputed from attrs, 4 FMA)
//   s3[g] = sum_{e: dst=g} silu(z3[e] + meshP[src[e]] + gridP[g])
// hb3 never materializes (was 195MB write + 195MB read); gridP[g] is
// block-uniform (one row read vs per-edge gather).
__global__ __launch_bounds__(256)
void segsum3(const unsigned short* __restrict__ z3,
             const unsigned short* __restrict__ mP,
             const unsigned short* __restrict__ gP,
             const float* __restrict__ attrs,
             const float* __restrict__ w0,
             const float* __restrict__ b0,
             const int* __restrict__ esrc,
             const unsigned* __restrict__ fill,
             const unsigned* __restrict__ slots,
             unsigned short* __restrict__ s1,
             unsigned short* __restrict__ s3)
{
    const int g = blockIdx.x;
    const int c = threadIdx.x;
    unsigned deg = fill[g]; if (deg > 64u) deg = 64u;
    float w0a[4], w0b[4];
    #pragma unroll
    for (int k = 0; k < 4; ++k) { w0a[k] = w0[k * 512 + c]; w0b[k] = w0[k * 512 + c + 256]; }
    const float b0a = b0[c], b0b = b0[c + 256];
    const float gpa = bf2f(gP[(size_t)g * 512 + c]);
    const float gpb = bf2f(gP[(size_t)g * 512 + c + 256]);
    float a0 = 0.f, a1 = 0.f, q0 = 0.f, q1 = 0.f;
    for (unsigned j = 0; j < deg; ++j) {
        const unsigned eid = slots[(size_t)g * 64 + j];
        const int se = esrc[eid];
        const float t0 = attrs[(size_t)eid * 4],     t1 = attrs[(size_t)eid * 4 + 1];
        const float t2 = attrs[(size_t)eid * 4 + 2], t3 = attrs[(size_t)eid * 4 + 3];
        a0 += silu_f(t0 * w0a[0] + t1 * w0a[1] + t2 * w0a[2] + t3 * w0a[3] + b0a);
        a1 += silu_f(t0 * w0b[0] + t1 * w0b[1] + t2 * w0b[2] + t3 * w0b[3] + b0b);
        const float za = bf2f(z3[(size_t)eid * 512 + c])
                       + bf2f(mP[(size_t)se * 512 + c]) + gpa;
        const float zb = bf2f(z3[(size_t)eid * 512 + c + 256])
                       + bf2f(mP[(size_t)se * 512 + c + 256]) + gpb;
        q0 += silu_f(za);
        q1 += silu_f(zb);
    }
    s1[(size_t)g * 512 + c]       = f2bf(a0);
    s1[(size_t)g * 512 + c + 256] = f2bf(a1);
    s3[(size_t)g * 512 + c]       = f2bf(q0);
    s3[(size_t)g * 512 + c + 256] = f2bf(q1);
}

// out[j] = base[j] + sum_k (v1[k] + v2[k]) * W[k*512 + j]   (v2 optional)
__global__ __launch_bounds__(256)
void vmb(const float* __restrict__ base, const float* __restrict__ v1,
         const float* __restrict__ v2, const float* __restrict__ W,
         float* __restrict__ out)
{
    const int j = blockIdx.x * 256 + threadIdx.x;
    if (j >= 512) return;
    float a = base[j];
    for (int k = 0; k < 512; ++k) {
        float vk = v1[k] + (v2 ? v2[k] : 0.f);
        a += vk * W[(size_t)k * 512 + j];
    }
    out[j] = a;
}

extern "C" void kernel_launch(void* const* d_in, const int* in_sizes, int n_in,
                              void* d_out, int out_size, void* d_ws, size_t ws_size,
                              hipStream_t stream)
{
    const float* mesh    = (const float*)d_in[0];
    const float* gridf   = (const float*)d_in[1];
    const float* attrs   = (const float*)d_in[2];
    const int*   esrc    = (const int*)d_in[3];
    const int*   edst    = (const int*)d_in[4];
    const float* emb_w0  = (const float*)d_in[5];
    const float* emb_b0  = (const float*)d_in[6];
    const float* emb_w1  = (const float*)d_in[7];
    const float* emb_b1  = (const float*)d_in[8];
    const float* edge_w0 = (const float*)d_in[9];
    const float* edge_b0 = (const float*)d_in[10];
    const float* edge_w1 = (const float*)d_in[11];
    const float* edge_b1 = (const float*)d_in[12];
    const float* node_w0 = (const float*)d_in[13];
    const float* node_b0 = (const float*)d_in[14];
    const float* node_w1 = (const float*)d_in[15];
    const float* node_b1 = (const float*)d_in[16];
    const float* out_w0  = (const float*)d_in[17];
    const float* out_b0  = (const float*)d_in[18];
    const float* out_w1  = (const float*)d_in[19];
    const float* out_b1  = (const float*)d_in[20];

    // ws (534 MB baseline footprint):
    //  region1 (200 MB): h1 (dead after G3''') -> gridP(66.7)+meshP(10.5)
    //                    (dead after segsum3) -> hb5 (G5' out)
    //  region2 (200 MB): z3 (dead after segsum3) -> hb7 (G7' out)
    //  r3 (133 MB): s1 | s3 (exact fit; dead after G5') -> out_w1T at base
    // d_out (122.8 MB) scratch until G8, fully overwritten by G8.
    char* ws = (char*)d_ws;
    unsigned short* h1  = (unsigned short*)ws;
    unsigned short* hb  = (unsigned short*)(ws + (size_t)NE * 512 * 2);   // z3 -> hb7
    char*           r3  = ws + (size_t)2 * NE * 512 * 2;   // 133,447,680 B
    unsigned short* gridP = h1;                               // after h1 dead
    unsigned short* meshP = (unsigned short*)(ws + 66723840); // region1 + 66.7MB
    unsigned short* hb5   = h1;                               // after gridP dead
    unsigned short* s1    = (unsigned short*)r3;
    unsigned short* s3    = (unsigned short*)(r3 + 66723840);
    unsigned short* out_w1T = (unsigned short*)r3;            // after s1 dead

    char* sc = (char*)d_out;                               // scratch until G8
    unsigned short* BwG5     = (unsigned short*)sc;                 // [512][1536]
    unsigned short* BwG7     = (unsigned short*)(sc +  1572864);    // [512][1024]
    unsigned short* W1T      = (unsigned short*)(sc +  2621440);
    unsigned short* W2T      = (unsigned short*)(sc +  3145728);
    unsigned short* W3T      = (unsigned short*)(sc +  3670016);
    unsigned short* WpT      = (unsigned short*)(sc +  4194304);
    unsigned short* nw0bT    = (unsigned short*)(sc +  4718592);
    unsigned short* ow0T     = (unsigned short*)(sc +  5242880);
    unsigned short* emb_w1b  = (unsigned short*)(sc +  5767168);
    unsigned short* edge_w1b = (unsigned short*)(sc +  6291456);
    unsigned short* node_w1b = (unsigned short*)(sc +  6815744);
    unsigned short* meshB    = (unsigned short*)(sc +  7340032);    // NM*512
    unsigned short* gridB    = (unsigned short*)(sc + 17827840);    // NG*512
    unsigned*       fillA    = (unsigned*)      (sc + 84551680);
    float*          zbias    = (float*)         (sc + 84812320);
    float*          bpp      = (float*)         (sc + 84814368);
    float*          c5       = (float*)         (sc + 84816416);
    float*          b7       = (float*)         (sc + 84818464);
    unsigned*       slots    = (unsigned*)      (sc + 84820512);    // NG*64 u32

    // zero fillA + zbias (contiguous)
    hipMemsetAsync(fillA, 0, 260640 + 2048, stream);

    dim3 blk(256);
    // transposes / converts into d_out scratch
    { dim3 g(8, 8); wconv<<<g, blk, 0, stream>>>(edge_w0,                      W1T, 512, 512, 512,  512); }
    { dim3 g(8, 8); wconv<<<g, blk, 0, stream>>>(edge_w0 + (size_t) 512 * 512, W2T, 512, 512, 512,  512); }
    { dim3 g(8, 8); wconv<<<g, blk, 0, stream>>>(edge_w0 + (size_t)1024 * 512, W3T, 512, 512, 512,  512); }
    { dim3 g(8, 8); wconv<<<g, blk, 0, stream>>>(node_w0,                      BwG5, 512, 512, 512, 1536); }  // nw0a
    { dim3 g(8, 8); wconv<<<g, blk, 0, stream>>>(node_w0 + (size_t)512 * 512,  nw0bT, 512, 512, 512, 512); }
    { dim3 g(8, 8); wconv<<<g, blk, 0, stream>>>(out_w0,  ow0T, 512, 512, 512,  512); }
    { dim3 g(8, 8); wconv<<<g, blk, 0, stream>>>(out_w0,  BwG7, 512, 512, 512, 1024); }   // G7 cols 0:512
    cvtb<<<128, blk, 0, stream>>>(emb_w1,  emb_w1b,  512 * 512 / 8);
    cvtb<<<128, blk, 0, stream>>>(edge_w1, edge_w1b, 512 * 512 / 8);
    cvtb<<<128, blk, 0, stream>>>(node_w1, node_w1b, 512 * 512 / 8);
    cvtb<<<(int)(((long long)NM * 512 / 8 + 255) / 256), blk, 0, stream>>>(mesh,  meshB, (long long)NM * 512 / 8);
    cvtb<<<(int)(((long long)NG * 512 / 8 + 255) / 256), blk, 0, stream>>>(gridf, gridB, (long long)NG * 512 / 8);
    fillslots<<<(NE + 255) / 256, blk, 0, stream>>>(edst, fillA, slots);
    // bias folds: bpp = edge_b0 + emb_b1@W3 ; c5 = (emb_b1+edge_b1)@nw0b ; b7 = out_b0 + node_b1@out_w0
    vmb<<<2, blk, 0, stream>>>(edge_b0, emb_b1, nullptr, edge_w0 + (size_t)1024 * 512, bpp);
    vmb<<<2, blk, 0, stream>>>(zbias, emb_b1, edge_b1, node_w0 + (size_t)512 * 512, c5);
    vmb<<<2, blk, 0, stream>>>(out_b0, node_b1, nullptr, out_w0, b7);

    // composite weights (stored transposed [n][k]):
    // WpT=(emb_w1@W3)^T ; U1=(emb_w1@nw0b)^T -> BwG5+512 ; U2=(edge_w1@nw0b)^T
    // -> BwG5+1024 ; U3=(node_w1@out_w0)^T -> BwG7+512
    gemm128<A_PLAIN, E_BIAS_BF16><<<16, blk, 0, stream>>>(W3T, nullptr, nullptr, emb_w1b, zbias, nullptr,
        512, 512, 512, 512, nullptr, WpT, nullptr);
    gemm128<A_PLAIN, E_BIAS_BF16><<<16, blk, 0, stream>>>(nw0bT, nullptr, nullptr, emb_w1b, zbias, nullptr,
        512, 512, 512, 1536, nullptr, BwG5 + 512, nullptr);
    gemm128<A_PLAIN, E_BIAS_BF16><<<16, blk, 0, stream>>>(nw0bT, nullptr, nullptr, edge_w1b, zbias, nullptr,
        512, 512, 512, 1536, nullptr, BwG5 + 1024, nullptr);
    gemm128<A_PLAIN, E_BIAS_BF16><<<16, blk, 0, stream>>>(ow0T, nullptr, nullptr, node_w1b, zbias, nullptr,
        512, 512, 512, 1024, nullptr, BwG7 + 512, nullptr);

    // L1: h1 = silu(attrs @ emb_w0 + b)   (vectorized)
    embed_l1<<<(int)(((long long)NE * 64 + 255) / 256), blk, 0, stream>>>(attrs, emb_w0, emb_b0, h1);

    const int nwgE = 4 * ((NE + 127) / 128);   // 6112
    const int nwgG = 4 * ((NG + 127) / 128);   // 2040
    const int nwgM = 4 * ((NM + 127) / 128);   // 324

    // G3''': z3 = h1 @ W'   (K=512; h1 L3-resident)
    gemm128<A_PLAIN, E_BIAS_BF16><<<nwgE, blk, 0, stream>>>(h1, nullptr, nullptr, WpT, zbias, nullptr,
        NE, 512, 512, 512, nullptr, hb, nullptr);
    // h1 dead -> gridP/meshP into region1
    gemm128<A_PLAIN, E_BIAS_BF16><<<nwgG, blk, 0, stream>>>(gridB, nullptr, nullptr, W2T, bpp, nullptr,
        NG, 512, 512, 512, nullptr, gridP, nullptr);
    gemm128<A_PLAIN, E_BIAS_BF16><<<nwgM, blk, 0, stream>>>(meshB, nullptr, nullptr, W1T, zbias, nullptr,
        NM, 512, 512, 512, nullptr, meshP, nullptr);
    // fused edge-finish + segment-sums (hb3 never materialized)
    segsum3<<<NG, blk, 0, stream>>>(hb, meshP, gridP, attrs, emb_w0, emb_b0,
        esrc, fillA, slots, s1, s3);
    // G5': hb5 = silu([gridB|s1|s3] @ [nw0a;U1;U2] + node_b0 + deg*c5)  (K=1536)
    gemm128<A_SEG, E_AGGSILU><<<nwgG, blk, 0, stream>>>(gridB, s1, s3, BwG5, node_b0, c5,
        NG, 512, 1536, 512, fillA, hb5, nullptr);
    // s1/s3 dead -> out_w1T into r3 for G8
    { dim3 g(8, 8); wconv<<<g, blk, 0, stream>>>(out_w1, out_w1T, 512, 471, 512, 512); }
    // G7': hb7 = silu([gridB|hb5] @ [ow0;U3] + b7)  (K=1024; G6 folded in)
    gemm128<A_SEG, E_SILU_BF16><<<nwgG, blk, 0, stream>>>(gridB, hb5, nullptr, BwG7, b7, nullptr,
        NG, 512, 1024, 512, nullptr, hb, nullptr);
    // G8: out = hb7 @ out_w1 + b (fp32, N=471; overwrites all d_out scratch)
    gemm128<A_PLAIN, E_OUT_F32><<<nwgG, blk, 0, stream>>>(hb, nullptr, nullptr, out_w1T, out_b1, nullptr,
        NG, NOUT, 512, NOUT, nullptr, nullptr, (float*)d_out);
}